// Round 10
// baseline (189.990 us; speedup 1.0000x reference)
//
#include <hip/hip_runtime.h>
#include <hip/hip_fp16.h>
#include <math.h>

// HieraFormer fused block:
//   transpose -> MFMA QKV proj -> fused attn (chunked swapped-MFMA QK^T ->
//   reg-resident fp16 z -> wave-local quadratic Newton -> chunked MFMA PV,
//   XOR-swizzled LDS, QT=32, 16 waves) -> LN+residual.
// B=2, D_MODEL=384, H=3, D_K=128, N=2048.
#define DM   384
#define NH   3
#define DK   128
#define NSEQ 2048
#define BATCH 2
#define NTOK (BATCH*NSEQ)      // 4096
#define SEG  (BATCH*NSEQ*DM)   // 1572864 elements
#define NEWTON_IT 8
#define QT   32                // q-rows per block
#define ZP   512               // LDS pitch in halves; conflicts handled by XOR swizzle
// byte-level swizzle: col_half ^ ((row&7)<<3)  (== byte ^ ((row&7)<<4))
#define ZIDX(row, ch) ((size_t)(row)*ZP + ((ch) ^ (((row)&7)<<3)))

typedef __attribute__((ext_vector_type(8))) short     bf16x8;
typedef __attribute__((ext_vector_type(4))) float     f32x4;
typedef __attribute__((ext_vector_type(8))) _Float16  h8;
typedef __attribute__((ext_vector_type(4))) _Float16  h4;
typedef __attribute__((ext_vector_type(2))) _Float16  h2v;

#if __has_builtin(__builtin_amdgcn_fdot2)
#define HAVE_FDOT2 1
#else
#define HAVE_FDOT2 0
#endif

__device__ __forceinline__ unsigned short f2bf(float f) {
  unsigned u = __builtin_bit_cast(unsigned, f);
  u += 0x7FFFu + ((u >> 16) & 1u);          // RNE
  return (unsigned short)(u >> 16);
}

// ---------------------------------------------------------------- transpose
__global__ __launch_bounds__(256) void transpose_k(const float* __restrict__ x,
                                                   float* __restrict__ xT,
                                                   unsigned short* __restrict__ xbf) {
  __shared__ float tile[32][33];
  int b  = blockIdx.z;
  int cB = blockIdx.y * 32;
  int nB = blockIdx.x * 32;
  int tx = threadIdx.x & 31, ty = threadIdx.x >> 5;
#pragma unroll
  for (int i = 0; i < 4; i++)
    tile[ty + i*8][tx] = x[((size_t)b*DM + cB + ty + i*8)*NSEQ + nB + tx];
  __syncthreads();
#pragma unroll
  for (int i = 0; i < 4; i++) {
    float v = tile[tx][ty + i*8];
    size_t row = (size_t)b*NSEQ + nB + ty + i*8;
    xT [row*DM + cB + tx] = v;
    xbf[row*DM + cB + tx] = f2bf(v);
  }
}

// ---------------------------------------------------------------- weight convert
__global__ __launch_bounds__(256) void wconv_k(const float* __restrict__ wq,
    const float* __restrict__ wk, const float* __restrict__ wv,
    unsigned short* __restrict__ wbf) {
  int pj = blockIdx.y;
  const float* src = (pj == 0) ? wq : (pj == 1) ? wk : wv;
  int i = (blockIdx.x * 256 + threadIdx.x) * 4;
  float4 v = *(const float4*)(src + i);
  ushort4 o;
  o.x = f2bf(v.x); o.y = f2bf(v.y); o.z = f2bf(v.z); o.w = f2bf(v.w);
  *(ushort4*)(wbf + (size_t)pj*DM*DM + i) = o;
}

// ---------------------------------------------------------------- MFMA projections
// Q,K -> bf16 [b][h][n][d];  V -> fp16 transposed VT [b][h][d][n].
__global__ __launch_bounds__(256) void proj_mfma_k(
    const unsigned short* __restrict__ xbf,   // [NTOK][DM]
    const unsigned short* __restrict__ wbf,   // [3][DM][DM]
    const float* __restrict__ bq, const float* __restrict__ bk, const float* __restrict__ bv,
    unsigned short* __restrict__ Qo, unsigned short* __restrict__ Ko,
    unsigned short* __restrict__ VTo) {      // VT stored as f16 bit-pattern
  int tid = threadIdx.x, lane = tid & 63, w = tid >> 6;
  int g = lane >> 4, li = lane & 15;
  int wr = w >> 1, wc = w & 1;
  int h  = blockIdx.y;
  int pj = blockIdx.z;
  const unsigned short* wp0 = wbf + (size_t)pj * DM * DM;
  const float* bias = (pj == 0) ? bq : (pj == 1) ? bk : bv;

  const unsigned short *Am, *Bn;
  int mB, nB;
  if (pj < 2) { Am = wp0; mB = h*128 + wr*64;          Bn = xbf; nB = blockIdx.x*128 + wc*64; }
  else        { Am = xbf; mB = blockIdx.x*128 + wr*64; Bn = wp0; nB = h*128 + wc*64; }

  f32x4 acc[4][4];
#pragma unroll
  for (int fi = 0; fi < 4; fi++)
#pragma unroll
    for (int fj = 0; fj < 4; fj++) acc[fi][fj] = (f32x4){0.f, 0.f, 0.f, 0.f};

#pragma unroll 2
  for (int ks = 0; ks < DM/32; ks++) {
    bf16x8 af[4], bf[4];
#pragma unroll
    for (int fi = 0; fi < 4; fi++)
      af[fi] = *(const bf16x8*)(Am + (size_t)(mB + fi*16 + li)*DM + ks*32 + g*8);
#pragma unroll
    for (int fj = 0; fj < 4; fj++)
      bf[fj] = *(const bf16x8*)(Bn + (size_t)(nB + fj*16 + li)*DM + ks*32 + g*8);
#pragma unroll
    for (int fi = 0; fi < 4; fi++)
#pragma unroll
      for (int fj = 0; fj < 4; fj++)
        acc[fi][fj] = __builtin_amdgcn_mfma_f32_16x16x32_bf16(af[fi], bf[fj], acc[fi][fj], 0, 0, 0);
  }

  if (pj < 2) {
    unsigned short* dst = (pj == 0) ? Qo : Ko;
#pragma unroll
    for (int fi = 0; fi < 4; fi++) {
      int o0 = mB + fi*16 + g*4;
      float4 bb = *(const float4*)(bias + o0);
      int d0 = o0 & 127;
#pragma unroll
      for (int fj = 0; fj < 4; fj++) {
        int tok = nB + fj*16 + li;
        int bb_ = tok >> 11, n = tok & 2047;
        ushort4 v4;
        v4.x = f2bf(acc[fi][fj][0] + bb.x);
        v4.y = f2bf(acc[fi][fj][1] + bb.y);
        v4.z = f2bf(acc[fi][fj][2] + bb.z);
        v4.w = f2bf(acc[fi][fj][3] + bb.w);
        *(ushort4*)(dst + ((size_t)(bb_*NH + h)*NSEQ + n)*DK + d0) = v4;
      }
    }
  } else {
#pragma unroll
    for (int fj = 0; fj < 4; fj++) {
      int o  = nB + fj*16 + li;
      float bb = bias[o];
      int d  = o & 127;
#pragma unroll
      for (int fi = 0; fi < 4; fi++) {
        int tok0 = mB + fi*16 + g*4;
        int bb_ = tok0 >> 11, n0 = tok0 & 2047;
        ushort4 v4;
        v4.x = __builtin_bit_cast(unsigned short, (_Float16)(acc[fi][fj][0] + bb));
        v4.y = __builtin_bit_cast(unsigned short, (_Float16)(acc[fi][fj][1] + bb));
        v4.z = __builtin_bit_cast(unsigned short, (_Float16)(acc[fi][fj][2] + bb));
        v4.w = __builtin_bit_cast(unsigned short, (_Float16)(acc[fi][fj][3] + bb));
        *(ushort4*)(VTo + ((size_t)(bb_*NH + h)*DK + d)*NSEQ + n0) = v4;
      }
    }
  }
}

// ---------------------------------------------------------------- entmax helpers
// scan f=sum d^2, g=sum d, c=support count over 16 half2 (one row slice)
__device__ __forceinline__ void scan16(const h2v* zh, float tau,
                                       float& f, float& g, float& c) {
  float ff = 0.f, gg = 0.f, cc = 0.f;
#if HAVE_FDOT2
  _Float16 th = (_Float16)tau;
  h2v t2 = {th, th};
  h2v zero2 = {(_Float16)0.f, (_Float16)0.f};
  h2v one2  = {(_Float16)1.f, (_Float16)1.f};
  h2v big2  = {(_Float16)60000.f, (_Float16)60000.f};
#pragma unroll
  for (int i = 0; i < 16; i++) {
    h2v d = __builtin_elementwise_max(zh[i] - t2, zero2);
    ff = __builtin_amdgcn_fdot2(d, d, ff, false);
    gg = __builtin_amdgcn_fdot2(d, one2, gg, false);
    h2v mm = __builtin_elementwise_min(d * big2, one2);
    cc = __builtin_amdgcn_fdot2(mm, one2, cc, false);
  }
#else
#pragma unroll
  for (int i = 0; i < 16; i++) {
#pragma unroll
    for (int j = 0; j < 2; j++) {
      float z = (float)zh[i][j];
      float d = fmaxf(z - tau, 0.f);
      ff = fmaf(d, d, ff);
      gg += d;
      cc += (d > 0.f) ? 1.f : 0.f;
    }
  }
#endif
  f = ff; g = gg; c = cc;
}

// frozen-support exact solve (Michelot step); Newton-back if overshot
__device__ __forceinline__ float nstep(float tau, float f, float g, float c, float m) {
  float num  = f - 1.0f;
  float disc = fmaxf(g*g - c*num, 0.f);
  float den  = (num >= 0.f) ? (g + sqrtf(disc)) : (2.0f * g);
  float t = tau + num / fmaxf(den, 1e-12f);
  return fminf(t, m - 0.01f);    // tau* <= m - 1/sqrt(2048); keeps support >= 1
}

// ---------------------------------------------------------------- fused attention
// Block = 32 q-rows of one (b,h); 1024 thr = 16 waves; grid 384 blocks.
// k in 4 chunks of 512. QK^T swapped (A=K, B=Q) -> packed h4 LDS stores; z fp16
// in REGISTERS (wave w owns q-rows w*2, w*2+1: 32 VGPRs). LDS: 2 x 32KiB
// ping-pong, XOR-swizzled. Newton wave-local. PV: wave = (qh, dt).
// launch_bounds(1024, 4): VGPR cap 128 >= ~90 live -> NO SPILLS (R9's (1024,8)
// capped at 64 and spilled the whole z state to scratch: 66 MB/dispatch HBM wr).
__global__ __launch_bounds__(1024, 4) void attn_k(const unsigned short* __restrict__ Qb,
    const unsigned short* __restrict__ Kb, const _Float16* __restrict__ VTb,
    float* __restrict__ AO) {
  __shared__ _Float16 zc[2][QT * ZP];     // 2 x 32768 B = 64 KiB

  int tid = threadIdx.x, lane = tid & 63, w = tid >> 6;   // w 0..15
  int g = lane >> 4, li = lane & 15;
  // bijective XCD swizzle: 384 blocks = 8 XCDs x 48 contiguous
  int swz = (blockIdx.x & 7) * 48 + (blockIdx.x >> 3);
  int bh = swz / (NSEQ/QT), qb = swz % (NSEQ/QT);         // NSEQ/QT = 64
  int qbase = qb * QT;
  const unsigned short* Qh  = Qb  + (size_t)bh * NSEQ * DK;
  const unsigned short* Kh  = Kb  + (size_t)bh * NSEQ * DK;
  const _Float16*       VTh = VTb + (size_t)bh * DK * NSEQ;
  const float zs = 0.044194173824159216f;   // 0.5 / sqrt(128)

  // Q B-frags: rows qbase + fj*16 + li, k-slice ks*32 + g*8 (persistent)
  bf16x8 bq[2][4];
#pragma unroll
  for (int fj = 0; fj < 2; fj++)
#pragma unroll
    for (int ks = 0; ks < 4; ks++)
      bq[fj][ks] = *(const bf16x8*)(Qh + (size_t)(qbase + fj*16 + li)*DK + ks*32 + g*8);

  // ---- Phase 1: QK^T in 4 chunks of 512 k (swapped: A=K rows, B=Q rows)
  // D row = k, col = q -> packed h4 store into z[q][k] (swizzled).
  h8 zr[2][4];   // [row r][chunk c]; wave w owns q rows w*2, w*2+1
#pragma unroll
  for (int c = 0; c < 4; c++) {
    _Float16* buf = zc[c & 1];
#pragma unroll
    for (int kt = 0; kt < 2; kt++) {
      int krow = c*512 + w*32 + kt*16 + li;
      bf16x8 bk[4];
#pragma unroll
      for (int ks = 0; ks < 4; ks++)
        bk[ks] = *(const bf16x8*)(Kh + (size_t)krow*DK + ks*32 + g*8);
#pragma unroll
      for (int fj = 0; fj < 2; fj++) {
        f32x4 za = (f32x4){0.f,0.f,0.f,0.f};
#pragma unroll
        for (int ks = 0; ks < 4; ks++)
          za = __builtin_amdgcn_mfma_f32_16x16x32_bf16(bk[ks], bq[fj][ks], za, 0, 0, 0);
        h4 p;
#pragma unroll
        for (int r = 0; r < 4; r++) p[r] = (_Float16)(za[r] * zs);
        *(h4*)(buf + ZIDX(fj*16 + li, w*32 + kt*16 + g*4)) = p;
      }
    }
    __syncthreads();   // z chunk staged (also fences prev chunk's reads)
#pragma unroll
    for (int r = 0; r < 2; r++)
      zr[r][c] = *(const h8*)(buf + ZIDX(w*2 + r, lane*8));
  }

  // ---- Phase 2: wave-local Newton on rows w*2, w*2+1 (no LDS, no barriers)
  float tau[2], mx[2];
#pragma unroll
  for (int r = 0; r < 2; r++) {
    union { h8 v[4]; h2v h[16]; } u;
#pragma unroll
    for (int c = 0; c < 4; c++) u.v[c] = zr[r][c];
    h2v m2 = u.h[0];
#pragma unroll
    for (int i = 1; i < 16; i++) m2 = __builtin_elementwise_max(m2, u.h[i]);
    float m = fmaxf((float)m2[0], (float)m2[1]);
#pragma unroll
    for (int off = 32; off > 0; off >>= 1) m = fmaxf(m, __shfl_xor(m, off));
    mx[r] = m;
    tau[r] = m - 1.0f;
  }
  for (int it = 0; it < NEWTON_IT; ++it) {
    float f[2], gg[2], cc[2];
#pragma unroll
    for (int r = 0; r < 2; r++) {
      union { h8 v[4]; h2v h[16]; } ur;
#pragma unroll
      for (int c = 0; c < 4; c++) ur.v[c] = zr[r][c];
      scan16(ur.h, tau[r], f[r], gg[r], cc[r]);
    }
#pragma unroll
    for (int off = 32; off > 0; off >>= 1) {
#pragma unroll
      for (int r = 0; r < 2; r++) {
        f[r]  += __shfl_xor(f[r],  off);
        gg[r] += __shfl_xor(gg[r], off);
        cc[r] += __shfl_xor(cc[r], off);
      }
    }
#pragma unroll
    for (int r = 0; r < 2; r++) tau[r] = nstep(tau[r], f[r], gg[r], cc[r], mx[r]);
  }

  // ---- Phase 3: PV in 4 chunks. P rebuilt from zr -> LDS (ping-pong); MFMA vs V^T.
  // wave = (qh, dt): A = P rows qh*16..+15, B = V^T rows dt*16..+15.
  int qh = w & 1, dt = w >> 1;
  f32x4 pacc = (f32x4){0.f,0.f,0.f,0.f};
#pragma unroll
  for (int c = 0; c < 4; c++) {
    _Float16* buf = zc[c & 1];
#pragma unroll
    for (int r = 0; r < 2; r++) {
      union { h8 v; h2v h[4]; } u;
      u.v = zr[r][c];
      _Float16 th = (_Float16)tau[r];
      h2v t2 = {th, th};
      h2v zero2 = {(_Float16)0.f, (_Float16)0.f};
#pragma unroll
      for (int j = 0; j < 4; j++) {
        h2v d = __builtin_elementwise_max(u.h[j] - t2, zero2);
        u.h[j] = d * d;
      }
      *(h8*)(buf + ZIDX(w*2 + r, lane*8)) = u.v;
    }
    __syncthreads();   // P chunk staged (also fences prev chunk's MFMA reads)
#pragma unroll
    for (int kk = 0; kk < 16; kk++) {
      h8 bv = *(const h8*)(VTh + (size_t)(dt*16 + li)*NSEQ + c*512 + kk*32 + g*8);
      h8 pa = *(const h8*)(buf + ZIDX(qh*16 + li, kk*32 + g*8));
      pacc = __builtin_amdgcn_mfma_f32_16x16x32_f16(pa, bv, pacc, 0, 0, 0);
    }
  }

  // ---- epilogue: out rows q = qbase + qh*16 + g*4 + r, col d = dt*16 + li
  int b = bh / NH, h = bh % NH;
#pragma unroll
  for (int r = 0; r < 4; r++)
    AO[((size_t)b*NSEQ + qbase + qh*16 + g*4 + r)*DM + h*DK + dt*16 + li] = pacc[r];
}

// ---------------------------------------------------------------- LN + residual
__global__ __launch_bounds__(256) void ln_k(const float* __restrict__ AO,
    const float* __restrict__ xT, const float* __restrict__ ga,
    const float* __restrict__ gb, float* __restrict__ outp) {
  int lane = threadIdx.x & 63;
  int wave = threadIdx.x >> 6;
  int row  = blockIdx.x * 4 + wave;
  const float* ao = AO + (size_t)row*DM;
  float2 c0 = *(const float2*)(ao + lane*2);
  float2 c1 = *(const float2*)(ao + 128 + lane*2);
  float2 c2 = *(const float2*)(ao + 256 + lane*2);
  float s  = c0.x + c0.y + c1.x + c1.y + c2.x + c2.y;
  float ss = c0.x*c0.x + c0.y*c0.y + c1.x*c1.x + c1.y*c1.y + c2.x*c2.x + c2.y*c2.y;
#pragma unroll
  for (int off = 32; off > 0; off >>= 1) {
    s  += __shfl_xor(s,  off);
    ss += __shfl_xor(ss, off);
  }
  float mean = s * (1.0f / 384.0f);
  float var  = (ss - 384.0f*mean*mean) * (1.0f / 383.0f);   // Bessel (n-1)
  var = fmaxf(var, 0.f);
  float inv = 1.0f / (sqrtf(var) + 1e-6f);                  // eps added to STD
  const float* xr = xT + (size_t)row*DM;
  float* op = outp + (size_t)row*DM;
#pragma unroll
  for (int ch = 0; ch < 3; ch++) {
    int i0 = ch*128 + lane*2;
    float2 g  = *(const float2*)(ga + i0);
    float2 bb = *(const float2*)(gb + i0);
    float2 xv = *(const float2*)(xr + i0);
    float2 av = (ch == 0) ? c0 : (ch == 1) ? c1 : c2;
    float2 o;
    o.x = g.x*(av.x - mean)*inv + bb.x + xv.x;
    o.y = g.y*(av.y - mean)*inv + bb.y + xv.y;
    *(float2*)(op + i0) = o;
  }
}

// ---------------------------------------------------------------- launch
extern "C" void kernel_launch(void* const* d_in, const int* in_sizes, int n_in,
                              void* d_out, int out_size, void* d_ws, size_t ws_size,
                              hipStream_t stream) {
  const float* x  = (const float*)d_in[0];
  const float* wq = (const float*)d_in[1];
  const float* bq = (const float*)d_in[2];
  const float* wk = (const float*)d_in[3];
  const float* bk = (const float*)d_in[4];
  const float* wv = (const float*)d_in[5];
  const float* bv = (const float*)d_in[6];
  const float* la = (const float*)d_in[7];
  const float* lb = (const float*)d_in[8];
  float* out = (float*)d_out;

  // ws: xT f32 | AO f32 | Qb bf16 | Kb bf16 | VT f16 | xbf bf16 | wbf bf16
  char* wsb = (char*)d_ws;
  float* xT = (float*)wsb;
  float* AO = (float*)(wsb + (size_t)SEG*4);
  unsigned short* Qb  = (unsigned short*)(wsb + (size_t)SEG*8);
  unsigned short* Kb  = (unsigned short*)(wsb + (size_t)SEG*8 + (size_t)SEG*2);
  unsigned short* VT  = (unsigned short*)(wsb + (size_t)SEG*8 + (size_t)SEG*4);
  unsigned short* xbf = (unsigned short*)(wsb + (size_t)SEG*8 + (size_t)SEG*6);
  unsigned short* wbf = (unsigned short*)(wsb + (size_t)SEG*8 + (size_t)SEG*8);

  hipLaunchKernelGGL(transpose_k, dim3(NSEQ/32, DM/32, BATCH), dim3(256), 0, stream,
                     x, xT, xbf);
  hipLaunchKernelGGL(wconv_k, dim3(DM*DM/1024, 3), dim3(256), 0, stream, wq, wk, wv, wbf);
  hipLaunchKernelGGL(proj_mfma_k, dim3(NTOK/128, NH, 3), dim3(256), 0, stream,
                     xbf, wbf, bq, bk, bv, Qb, Kb, VT);
  hipLaunchKernelGGL(attn_k, dim3(BATCH*NH*(NSEQ/QT)), dim3(1024), 0, stream,
                     Qb, Kb, (const _Float16*)VT, AO);
  hipLaunchKernelGGL(ln_k, dim3(BATCH*NSEQ/4), dim3(256), 0, stream, AO, xT, la, lb, out);
}

// Round 11
// 154.699 us; speedup vs baseline: 1.2281x; 1.2281x over previous
//
#include <hip/hip_runtime.h>
#include <hip/hip_fp16.h>
#include <math.h>

// HieraFormer fused block:
//   transpose -> MFMA QKV proj -> fused attn (chunked swapped-MFMA QK^T ->
//   reg-resident fp16 z -> wave-local quadratic Newton -> chunked MFMA PV,
//   ping-pong LDS, QT=32, 8 waves) -> LN+residual.
// B=2, D_MODEL=384, H=3, D_K=128, N=2048.
#define DM   384
#define NH   3
#define DK   128
#define NSEQ 2048
#define BATCH 2
#define NTOK (BATCH*NSEQ)      // 4096
#define SEG  (BATCH*NSEQ*DM)   // 1572864 elements
#define NEWTON_IT 6
#define QT   32                // q-rows per block
#define ZP   520               // LDS pitch in halves (512 + 8); all rows 16B-aligned

typedef __attribute__((ext_vector_type(8))) short     bf16x8;
typedef __attribute__((ext_vector_type(4))) float     f32x4;
typedef __attribute__((ext_vector_type(8))) _Float16  h8;
typedef __attribute__((ext_vector_type(4))) _Float16  h4;
typedef __attribute__((ext_vector_type(2))) _Float16  h2v;

#if __has_builtin(__builtin_amdgcn_fdot2)
#define HAVE_FDOT2 1
#else
#define HAVE_FDOT2 0
#endif

__device__ __forceinline__ unsigned short f2bf(float f) {
  unsigned u = __builtin_bit_cast(unsigned, f);
  u += 0x7FFFu + ((u >> 16) & 1u);          // RNE
  return (unsigned short)(u >> 16);
}

// ---------------------------------------------------------------- transpose
__global__ __launch_bounds__(256) void transpose_k(const float* __restrict__ x,
                                                   float* __restrict__ xT,
                                                   unsigned short* __restrict__ xbf) {
  __shared__ float tile[32][33];
  int b  = blockIdx.z;
  int cB = blockIdx.y * 32;
  int nB = blockIdx.x * 32;
  int tx = threadIdx.x & 31, ty = threadIdx.x >> 5;
#pragma unroll
  for (int i = 0; i < 4; i++)
    tile[ty + i*8][tx] = x[((size_t)b*DM + cB + ty + i*8)*NSEQ + nB + tx];
  __syncthreads();
#pragma unroll
  for (int i = 0; i < 4; i++) {
    float v = tile[tx][ty + i*8];
    size_t row = (size_t)b*NSEQ + nB + ty + i*8;
    xT [row*DM + cB + tx] = v;
    xbf[row*DM + cB + tx] = f2bf(v);
  }
}

// ---------------------------------------------------------------- weight convert
__global__ __launch_bounds__(256) void wconv_k(const float* __restrict__ wq,
    const float* __restrict__ wk, const float* __restrict__ wv,
    unsigned short* __restrict__ wbf) {
  int pj = blockIdx.y;
  const float* src = (pj == 0) ? wq : (pj == 1) ? wk : wv;
  int i = (blockIdx.x * 256 + threadIdx.x) * 4;
  float4 v = *(const float4*)(src + i);
  ushort4 o;
  o.x = f2bf(v.x); o.y = f2bf(v.y); o.z = f2bf(v.z); o.w = f2bf(v.w);
  *(ushort4*)(wbf + (size_t)pj*DM*DM + i) = o;
}

// ---------------------------------------------------------------- MFMA projections
// Q,K -> bf16 [b][h][n][d];  V -> fp16 transposed VT [b][h][d][n].
__global__ __launch_bounds__(256) void proj_mfma_k(
    const unsigned short* __restrict__ xbf,   // [NTOK][DM]
    const unsigned short* __restrict__ wbf,   // [3][DM][DM]
    const float* __restrict__ bq, const float* __restrict__ bk, const float* __restrict__ bv,
    unsigned short* __restrict__ Qo, unsigned short* __restrict__ Ko,
    unsigned short* __restrict__ VTo) {      // VT stored as f16 bit-pattern
  int tid = threadIdx.x, lane = tid & 63, w = tid >> 6;
  int g = lane >> 4, li = lane & 15;
  int wr = w >> 1, wc = w & 1;
  int h  = blockIdx.y;
  int pj = blockIdx.z;
  const unsigned short* wp0 = wbf + (size_t)pj * DM * DM;
  const float* bias = (pj == 0) ? bq : (pj == 1) ? bk : bv;

  const unsigned short *Am, *Bn;
  int mB, nB;
  if (pj < 2) { Am = wp0; mB = h*128 + wr*64;          Bn = xbf; nB = blockIdx.x*128 + wc*64; }
  else        { Am = xbf; mB = blockIdx.x*128 + wr*64; Bn = wp0; nB = h*128 + wc*64; }

  f32x4 acc[4][4];
#pragma unroll
  for (int fi = 0; fi < 4; fi++)
#pragma unroll
    for (int fj = 0; fj < 4; fj++) acc[fi][fj] = (f32x4){0.f, 0.f, 0.f, 0.f};

#pragma unroll 2
  for (int ks = 0; ks < DM/32; ks++) {
    bf16x8 af[4], bf[4];
#pragma unroll
    for (int fi = 0; fi < 4; fi++)
      af[fi] = *(const bf16x8*)(Am + (size_t)(mB + fi*16 + li)*DM + ks*32 + g*8);
#pragma unroll
    for (int fj = 0; fj < 4; fj++)
      bf[fj] = *(const bf16x8*)(Bn + (size_t)(nB + fj*16 + li)*DM + ks*32 + g*8);
#pragma unroll
    for (int fi = 0; fi < 4; fi++)
#pragma unroll
      for (int fj = 0; fj < 4; fj++)
        acc[fi][fj] = __builtin_amdgcn_mfma_f32_16x16x32_bf16(af[fi], bf[fj], acc[fi][fj], 0, 0, 0);
  }

  if (pj < 2) {
    unsigned short* dst = (pj == 0) ? Qo : Ko;
#pragma unroll
    for (int fi = 0; fi < 4; fi++) {
      int o0 = mB + fi*16 + g*4;
      float4 bb = *(const float4*)(bias + o0);
      int d0 = o0 & 127;
#pragma unroll
      for (int fj = 0; fj < 4; fj++) {
        int tok = nB + fj*16 + li;
        int bb_ = tok >> 11, n = tok & 2047;
        ushort4 v4;
        v4.x = f2bf(acc[fi][fj][0] + bb.x);
        v4.y = f2bf(acc[fi][fj][1] + bb.y);
        v4.z = f2bf(acc[fi][fj][2] + bb.z);
        v4.w = f2bf(acc[fi][fj][3] + bb.w);
        *(ushort4*)(dst + ((size_t)(bb_*NH + h)*NSEQ + n)*DK + d0) = v4;
      }
    }
  } else {
#pragma unroll
    for (int fj = 0; fj < 4; fj++) {
      int o  = nB + fj*16 + li;
      float bb = bias[o];
      int d  = o & 127;
#pragma unroll
      for (int fi = 0; fi < 4; fi++) {
        int tok0 = mB + fi*16 + g*4;
        int bb_ = tok0 >> 11, n0 = tok0 & 2047;
        ushort4 v4;
        v4.x = __builtin_bit_cast(unsigned short, (_Float16)(acc[fi][fj][0] + bb));
        v4.y = __builtin_bit_cast(unsigned short, (_Float16)(acc[fi][fj][1] + bb));
        v4.z = __builtin_bit_cast(unsigned short, (_Float16)(acc[fi][fj][2] + bb));
        v4.w = __builtin_bit_cast(unsigned short, (_Float16)(acc[fi][fj][3] + bb));
        *(ushort4*)(VTo + ((size_t)(bb_*NH + h)*DK + d)*NSEQ + n0) = v4;
      }
    }
  }
}

// ---------------------------------------------------------------- entmax helpers
// scan f=sum d^2, g=sum d, c=support count over 16 half2 (one row slice)
__device__ __forceinline__ void scan16(const h2v* zh, float tau,
                                       float& f, float& g, float& c) {
  float ff = 0.f, gg = 0.f, cc = 0.f;
#if HAVE_FDOT2
  _Float16 th = (_Float16)tau;
  h2v t2 = {th, th};
  h2v zero2 = {(_Float16)0.f, (_Float16)0.f};
  h2v one2  = {(_Float16)1.f, (_Float16)1.f};
  h2v big2  = {(_Float16)60000.f, (_Float16)60000.f};
#pragma unroll
  for (int i = 0; i < 16; i++) {
    h2v d = __builtin_elementwise_max(zh[i] - t2, zero2);
    ff = __builtin_amdgcn_fdot2(d, d, ff, false);
    gg = __builtin_amdgcn_fdot2(d, one2, gg, false);
    h2v mm = __builtin_elementwise_min(d * big2, one2);
    cc = __builtin_amdgcn_fdot2(mm, one2, cc, false);
  }
#else
#pragma unroll
  for (int i = 0; i < 16; i++) {
#pragma unroll
    for (int j = 0; j < 2; j++) {
      float z = (float)zh[i][j];
      float d = fmaxf(z - tau, 0.f);
      ff = fmaf(d, d, ff);
      gg += d;
      cc += (d > 0.f) ? 1.f : 0.f;
    }
  }
#endif
  f = ff; g = gg; c = cc;
}

// frozen-support exact solve (Michelot step); Newton-back if overshot
__device__ __forceinline__ float nstep(float tau, float f, float g, float c, float m) {
  float num  = f - 1.0f;
  float disc = fmaxf(g*g - c*num, 0.f);
  float den  = (num >= 0.f) ? (g + sqrtf(disc)) : (2.0f * g);
  float t = tau + num / fmaxf(den, 1e-12f);
  return fminf(t, m - 0.01f);    // tau* <= m - 1/sqrt(2048); keeps support >= 1
}

// ---------------------------------------------------------------- fused attention
// Block = 32 q-rows of one (b,h); 512 thr = 8 waves; grid 384 blocks.
// k in 4 chunks of 512. QK^T SWAPPED (A=K, B=Q): lane's 4 acc = 4 consecutive
// k at fixed q -> one packed 8B h4 LDS store. z fp16 in REGISTERS (wave w owns
// q-rows w*4..w*4+3: 64 VGPRs). Ping-pong LDS (2x33KB) -> 1 barrier/chunk
// (8 total vs R7's 16). Newton wave-local. PV: wave w owns d [w*16, w*16+16).
// launch_bounds(512,3): VGPR cap 170 >= ~140 live -> true VGPR residency
// (R7's (512,4)=128 cap squeezed to 60 arch VGPRs; R9's (1024,8)=64 spilled).
__global__ __launch_bounds__(512, 3) void attn_k(const unsigned short* __restrict__ Qb,
    const unsigned short* __restrict__ Kb, const _Float16* __restrict__ VTb,
    float* __restrict__ AO) {
  __shared__ _Float16 zc[2][QT * ZP];     // 2 x 33280 B

  int tid = threadIdx.x, lane = tid & 63, w = tid >> 6;   // w 0..7
  int g = lane >> 4, li = lane & 15;
  // bijective XCD swizzle: 384 blocks = 8 XCDs x 48 contiguous
  int swz = (blockIdx.x & 7) * 48 + (blockIdx.x >> 3);
  int bh = swz / (NSEQ/QT), qb = swz % (NSEQ/QT);         // NSEQ/QT = 64
  int qbase = qb * QT;
  const unsigned short* Qh  = Qb  + (size_t)bh * NSEQ * DK;
  const unsigned short* Kh  = Kb  + (size_t)bh * NSEQ * DK;
  const _Float16*       VTh = VTb + (size_t)bh * DK * NSEQ;
  const float zs = 0.044194173824159216f;   // 0.5 / sqrt(128)

  // Q B-frags: cols q = qbase + fj*16 + li, k-slice ks*32 + g*8 (persistent)
  bf16x8 bq[2][4];
#pragma unroll
  for (int fj = 0; fj < 2; fj++)
#pragma unroll
    for (int ks = 0; ks < 4; ks++)
      bq[fj][ks] = *(const bf16x8*)(Qh + (size_t)(qbase + fj*16 + li)*DK + ks*32 + g*8);

  // ---- Phase 1: QK^T in 4 chunks of 512 k (swapped: A=K rows, B=Q cols)
  // D row = k = kt*16+g*4+r, col = q = fj*16+li -> packed h4 store z[q][k].
  h8 zr[4][4];   // [row r][chunk c]; wave w owns q rows w*4..w*4+3
#pragma unroll
  for (int c = 0; c < 4; c++) {
    _Float16* buf = zc[c & 1];
#pragma unroll
    for (int kt = 0; kt < 4; kt++) {
      int krow = c*512 + w*64 + kt*16 + li;
      bf16x8 bk[4];
#pragma unroll
      for (int ks = 0; ks < 4; ks++)
        bk[ks] = *(const bf16x8*)(Kh + (size_t)krow*DK + ks*32 + g*8);
#pragma unroll
      for (int fj = 0; fj < 2; fj++) {
        f32x4 za = (f32x4){0.f,0.f,0.f,0.f};
#pragma unroll
        for (int ks = 0; ks < 4; ks++)
          za = __builtin_amdgcn_mfma_f32_16x16x32_bf16(bk[ks], bq[fj][ks], za, 0, 0, 0);
        h4 p;
#pragma unroll
        for (int r = 0; r < 4; r++) p[r] = (_Float16)(za[r] * zs);
        *(h4*)(buf + (size_t)(fj*16 + li)*ZP + w*64 + kt*16 + g*4) = p;
      }
    }
    __syncthreads();   // chunk staged; ping-pong makes one barrier sufficient
#pragma unroll
    for (int r = 0; r < 4; r++)
      zr[r][c] = *(const h8*)(buf + (size_t)(w*4 + r)*ZP + lane*8);
  }

  // ---- Phase 2: wave-local Newton on rows w*4..w*4+3 (no LDS, no barriers)
  float tau[4], mx[4];
#pragma unroll
  for (int r = 0; r < 4; r++) {
    union { h8 v[4]; h2v h[16]; } u;
#pragma unroll
    for (int c = 0; c < 4; c++) u.v[c] = zr[r][c];
    h2v m2 = u.h[0];
#pragma unroll
    for (int i = 1; i < 16; i++) m2 = __builtin_elementwise_max(m2, u.h[i]);
    float m = fmaxf((float)m2[0], (float)m2[1]);
#pragma unroll
    for (int off = 32; off > 0; off >>= 1) m = fmaxf(m, __shfl_xor(m, off));
    mx[r] = m;
    tau[r] = m - 1.0f;
  }
  for (int it = 0; it < NEWTON_IT; ++it) {
    float f[4], gg[4], cc[4];
#pragma unroll
    for (int r = 0; r < 4; r++) {
      union { h8 v[4]; h2v h[16]; } ur;
#pragma unroll
      for (int c = 0; c < 4; c++) ur.v[c] = zr[r][c];
      scan16(ur.h, tau[r], f[r], gg[r], cc[r]);
    }
#pragma unroll
    for (int off = 32; off > 0; off >>= 1) {
#pragma unroll
      for (int r = 0; r < 4; r++) {
        f[r]  += __shfl_xor(f[r],  off);
        gg[r] += __shfl_xor(gg[r], off);
        cc[r] += __shfl_xor(cc[r], off);
      }
    }
#pragma unroll
    for (int r = 0; r < 4; r++) tau[r] = nstep(tau[r], f[r], gg[r], cc[r], mx[r]);
  }

  // ---- Phase 3: PV in 4 chunks. P rebuilt from zr -> LDS (ping-pong); MFMA vs V^T.
  // wave w owns d in [w*16, w*16+16); pacc[fi] = q-halves.
  int d0 = w * 16;
  f32x4 pacc[2];
  pacc[0] = (f32x4){0.f,0.f,0.f,0.f};
  pacc[1] = (f32x4){0.f,0.f,0.f,0.f};
#pragma unroll
  for (int c = 0; c < 4; c++) {
    _Float16* buf = zc[c & 1];
#pragma unroll
    for (int r = 0; r < 4; r++) {
      union { h8 v; h2v h[4]; } u;
      u.v = zr[r][c];
      _Float16 th = (_Float16)tau[r];
      h2v t2 = {th, th};
      h2v zero2 = {(_Float16)0.f, (_Float16)0.f};
#pragma unroll
      for (int j = 0; j < 4; j++) {
        h2v d = __builtin_elementwise_max(u.h[j] - t2, zero2);
        u.h[j] = d * d;
      }
      *(h8*)(buf + (size_t)(w*4 + r)*ZP + lane*8) = u.v;
    }
    __syncthreads();   // P chunk staged; ping-pong protects prev chunk's reads
#pragma unroll
    for (int kk = 0; kk < 16; kk++) {
      h8 bv  = *(const h8*)(VTh + (size_t)(d0 + li)*NSEQ + c*512 + kk*32 + g*8);
      h8 pa0 = *(const h8*)(buf + (size_t)li*ZP + kk*32 + g*8);
      h8 pa1 = *(const h8*)(buf + (size_t)(16 + li)*ZP + kk*32 + g*8);
      pacc[0] = __builtin_amdgcn_mfma_f32_16x16x32_f16(pa0, bv, pacc[0], 0, 0, 0);
      pacc[1] = __builtin_amdgcn_mfma_f32_16x16x32_f16(pa1, bv, pacc[1], 0, 0, 0);
    }
  }

  // ---- epilogue: out rows q = qbase + fi*16 + g*4 + r, col d = d0 + li
  int b = bh / NH, h = bh % NH;
#pragma unroll
  for (int fi = 0; fi < 2; fi++)
#pragma unroll
    for (int r = 0; r < 4; r++)
      AO[((size_t)b*NSEQ + qbase + fi*16 + g*4 + r)*DM + h*DK + d0 + li] = pacc[fi][r];
}

// ---------------------------------------------------------------- LN + residual
__global__ __launch_bounds__(256) void ln_k(const float* __restrict__ AO,
    const float* __restrict__ xT, const float* __restrict__ ga,
    const float* __restrict__ gb, float* __restrict__ outp) {
  int lane = threadIdx.x & 63;
  int wave = threadIdx.x >> 6;
  int row  = blockIdx.x * 4 + wave;
  const float* ao = AO + (size_t)row*DM;
  float2 c0 = *(const float2*)(ao + lane*2);
  float2 c1 = *(const float2*)(ao + 128 + lane*2);
  float2 c2 = *(const float2*)(ao + 256 + lane*2);
  float s  = c0.x + c0.y + c1.x + c1.y + c2.x + c2.y;
  float ss = c0.x*c0.x + c0.y*c0.y + c1.x*c1.x + c1.y*c1.y + c2.x*c2.x + c2.y*c2.y;
#pragma unroll
  for (int off = 32; off > 0; off >>= 1) {
    s  += __shfl_xor(s,  off);
    ss += __shfl_xor(ss, off);
  }
  float mean = s * (1.0f / 384.0f);
  float var  = (ss - 384.0f*mean*mean) * (1.0f / 383.0f);   // Bessel (n-1)
  var = fmaxf(var, 0.f);
  float inv = 1.0f / (sqrtf(var) + 1e-6f);                  // eps added to STD
  const float* xr = xT + (size_t)row*DM;
  float* op = outp + (size_t)row*DM;
#pragma unroll
  for (int ch = 0; ch < 3; ch++) {
    int i0 = ch*128 + lane*2;
    float2 g  = *(const float2*)(ga + i0);
    float2 bb = *(const float2*)(gb + i0);
    float2 xv = *(const float2*)(xr + i0);
    float2 av = (ch == 0) ? c0 : (ch == 1) ? c1 : c2;
    float2 o;
    o.x = g.x*(av.x - mean)*inv + bb.x + xv.x;
    o.y = g.y*(av.y - mean)*inv + bb.y + xv.y;
    *(float2*)(op + i0) = o;
  }
}

// ---------------------------------------------------------------- launch
extern "C" void kernel_launch(void* const* d_in, const int* in_sizes, int n_in,
                              void* d_out, int out_size, void* d_ws, size_t ws_size,
                              hipStream_t stream) {
  const float* x  = (const float*)d_in[0];
  const float* wq = (const float*)d_in[1];
  const float* bq = (const float*)d_in[2];
  const float* wk = (const float*)d_in[3];
  const float* bk = (const float*)d_in[4];
  const float* wv = (const float*)d_in[5];
  const float* bv = (const float*)d_in[6];
  const float* la = (const float*)d_in[7];
  const float* lb = (const float*)d_in[8];
  float* out = (float*)d_out;

  // ws: xT f32 | AO f32 | Qb bf16 | Kb bf16 | VT f16 | xbf bf16 | wbf bf16
  char* wsb = (char*)d_ws;
  float* xT = (float*)wsb;
  float* AO = (float*)(wsb + (size_t)SEG*4);
  unsigned short* Qb  = (unsigned short*)(wsb + (size_t)SEG*8);
  unsigned short* Kb  = (unsigned short*)(wsb + (size_t)SEG*8 + (size_t)SEG*2);
  unsigned short* VT  = (unsigned short*)(wsb + (size_t)SEG*8 + (size_t)SEG*4);
  unsigned short* xbf = (unsigned short*)(wsb + (size_t)SEG*8 + (size_t)SEG*6);
  unsigned short* wbf = (unsigned short*)(wsb + (size_t)SEG*8 + (size_t)SEG*8);

  hipLaunchKernelGGL(transpose_k, dim3(NSEQ/32, DM/32, BATCH), dim3(256), 0, stream,
                     x, xT, xbf);
  hipLaunchKernelGGL(wconv_k, dim3(DM*DM/1024, 3), dim3(256), 0, stream, wq, wk, wv, wbf);
  hipLaunchKernelGGL(proj_mfma_k, dim3(NTOK/128, NH, 3), dim3(256), 0, stream,
                     xbf, wbf, bq, bk, bv, Qb, Kb, VT);
  hipLaunchKernelGGL(attn_k, dim3(BATCH*NH*(NSEQ/QT)), dim3(512), 0, stream,
                     Qb, Kb, (const _Float16*)VT, AO);
  hipLaunchKernelGGL(ln_k, dim3(BATCH*NSEQ/4), dim3(256), 0, stream, AO, xT, la, lb, out);
}

// Round 12
// 134.532 us; speedup vs baseline: 1.4122x; 1.1499x over previous
//
#include <hip/hip_runtime.h>
#include <hip/hip_fp16.h>
#include <math.h>

// HieraFormer fused block:
//   transpose -> MFMA QKV proj -> fused attn (256-thr blocks, QT=16, 3 blocks/CU:
//   chunked swapped-MFMA QK^T -> reg-resident fp16 z -> wave-local quadratic
//   Newton -> chunked MFMA PV, ping-pong LDS) -> LN+residual.
// B=2, D_MODEL=384, H=3, D_K=128, N=2048.
#define DM   384
#define NH   3
#define DK   128
#define NSEQ 2048
#define BATCH 2
#define NTOK (BATCH*NSEQ)      // 4096
#define SEG  (BATCH*NSEQ*DM)   // 1572864 elements
#define NEWTON_IT 6
#define QT   16                // q-rows per block
#define ZP   520               // LDS pitch in halves (512 + 8); rows 16B-aligned

typedef __attribute__((ext_vector_type(8))) short     bf16x8;
typedef __attribute__((ext_vector_type(4))) float     f32x4;
typedef __attribute__((ext_vector_type(8))) _Float16  h8;
typedef __attribute__((ext_vector_type(4))) _Float16  h4;
typedef __attribute__((ext_vector_type(2))) _Float16  h2v;

#if __has_builtin(__builtin_amdgcn_fdot2)
#define HAVE_FDOT2 1
#else
#define HAVE_FDOT2 0
#endif

__device__ __forceinline__ unsigned short f2bf(float f) {
  unsigned u = __builtin_bit_cast(unsigned, f);
  u += 0x7FFFu + ((u >> 16) & 1u);          // RNE
  return (unsigned short)(u >> 16);
}

// ---------------------------------------------------------------- transpose
__global__ __launch_bounds__(256) void transpose_k(const float* __restrict__ x,
                                                   float* __restrict__ xT,
                                                   unsigned short* __restrict__ xbf) {
  __shared__ float tile[32][33];
  int b  = blockIdx.z;
  int cB = blockIdx.y * 32;
  int nB = blockIdx.x * 32;
  int tx = threadIdx.x & 31, ty = threadIdx.x >> 5;
#pragma unroll
  for (int i = 0; i < 4; i++)
    tile[ty + i*8][tx] = x[((size_t)b*DM + cB + ty + i*8)*NSEQ + nB + tx];
  __syncthreads();
#pragma unroll
  for (int i = 0; i < 4; i++) {
    float v = tile[tx][ty + i*8];
    size_t row = (size_t)b*NSEQ + nB + ty + i*8;
    xT [row*DM + cB + tx] = v;
    xbf[row*DM + cB + tx] = f2bf(v);
  }
}

// ---------------------------------------------------------------- weight convert
__global__ __launch_bounds__(256) void wconv_k(const float* __restrict__ wq,
    const float* __restrict__ wk, const float* __restrict__ wv,
    unsigned short* __restrict__ wbf) {
  int pj = blockIdx.y;
  const float* src = (pj == 0) ? wq : (pj == 1) ? wk : wv;
  int i = (blockIdx.x * 256 + threadIdx.x) * 4;
  float4 v = *(const float4*)(src + i);
  ushort4 o;
  o.x = f2bf(v.x); o.y = f2bf(v.y); o.z = f2bf(v.z); o.w = f2bf(v.w);
  *(ushort4*)(wbf + (size_t)pj*DM*DM + i) = o;
}

// ---------------------------------------------------------------- MFMA projections
// Q,K -> bf16 [b][h][n][d];  V -> fp16 transposed VT [b][h][d][n].
__global__ __launch_bounds__(256) void proj_mfma_k(
    const unsigned short* __restrict__ xbf,   // [NTOK][DM]
    const unsigned short* __restrict__ wbf,   // [3][DM][DM]
    const float* __restrict__ bq, const float* __restrict__ bk, const float* __restrict__ bv,
    unsigned short* __restrict__ Qo, unsigned short* __restrict__ Ko,
    unsigned short* __restrict__ VTo) {      // VT stored as f16 bit-pattern
  int tid = threadIdx.x, lane = tid & 63, w = tid >> 6;
  int g = lane >> 4, li = lane & 15;
  int wr = w >> 1, wc = w & 1;
  int h  = blockIdx.y;
  int pj = blockIdx.z;
  const unsigned short* wp0 = wbf + (size_t)pj * DM * DM;
  const float* bias = (pj == 0) ? bq : (pj == 1) ? bk : bv;

  const unsigned short *Am, *Bn;
  int mB, nB;
  if (pj < 2) { Am = wp0; mB = h*128 + wr*64;          Bn = xbf; nB = blockIdx.x*128 + wc*64; }
  else        { Am = xbf; mB = blockIdx.x*128 + wr*64; Bn = wp0; nB = h*128 + wc*64; }

  f32x4 acc[4][4];
#pragma unroll
  for (int fi = 0; fi < 4; fi++)
#pragma unroll
    for (int fj = 0; fj < 4; fj++) acc[fi][fj] = (f32x4){0.f, 0.f, 0.f, 0.f};

#pragma unroll 2
  for (int ks = 0; ks < DM/32; ks++) {
    bf16x8 af[4], bf[4];
#pragma unroll
    for (int fi = 0; fi < 4; fi++)
      af[fi] = *(const bf16x8*)(Am + (size_t)(mB + fi*16 + li)*DM + ks*32 + g*8);
#pragma unroll
    for (int fj = 0; fj < 4; fj++)
      bf[fj] = *(const bf16x8*)(Bn + (size_t)(nB + fj*16 + li)*DM + ks*32 + g*8);
#pragma unroll
    for (int fi = 0; fi < 4; fi++)
#pragma unroll
      for (int fj = 0; fj < 4; fj++)
        acc[fi][fj] = __builtin_amdgcn_mfma_f32_16x16x32_bf16(af[fi], bf[fj], acc[fi][fj], 0, 0, 0);
  }

  if (pj < 2) {
    unsigned short* dst = (pj == 0) ? Qo : Ko;
#pragma unroll
    for (int fi = 0; fi < 4; fi++) {
      int o0 = mB + fi*16 + g*4;
      float4 bb = *(const float4*)(bias + o0);
      int d0 = o0 & 127;
#pragma unroll
      for (int fj = 0; fj < 4; fj++) {
        int tok = nB + fj*16 + li;
        int bb_ = tok >> 11, n = tok & 2047;
        ushort4 v4;
        v4.x = f2bf(acc[fi][fj][0] + bb.x);
        v4.y = f2bf(acc[fi][fj][1] + bb.y);
        v4.z = f2bf(acc[fi][fj][2] + bb.z);
        v4.w = f2bf(acc[fi][fj][3] + bb.w);
        *(ushort4*)(dst + ((size_t)(bb_*NH + h)*NSEQ + n)*DK + d0) = v4;
      }
    }
  } else {
#pragma unroll
    for (int fj = 0; fj < 4; fj++) {
      int o  = nB + fj*16 + li;
      float bb = bias[o];
      int d  = o & 127;
#pragma unroll
      for (int fi = 0; fi < 4; fi++) {
        int tok0 = mB + fi*16 + g*4;
        int bb_ = tok0 >> 11, n0 = tok0 & 2047;
        ushort4 v4;
        v4.x = __builtin_bit_cast(unsigned short, (_Float16)(acc[fi][fj][0] + bb));
        v4.y = __builtin_bit_cast(unsigned short, (_Float16)(acc[fi][fj][1] + bb));
        v4.z = __builtin_bit_cast(unsigned short, (_Float16)(acc[fi][fj][2] + bb));
        v4.w = __builtin_bit_cast(unsigned short, (_Float16)(acc[fi][fj][3] + bb));
        *(ushort4*)(VTo + ((size_t)(bb_*NH + h)*DK + d)*NSEQ + n0) = v4;
      }
    }
  }
}

// ---------------------------------------------------------------- entmax helpers
// scan f=sum d^2, g=sum d, c=support count over 16 half2 (one row slice)
__device__ __forceinline__ void scan16(const h2v* zh, float tau,
                                       float& f, float& g, float& c) {
  float ff = 0.f, gg = 0.f, cc = 0.f;
#if HAVE_FDOT2
  _Float16 th = (_Float16)tau;
  h2v t2 = {th, th};
  h2v zero2 = {(_Float16)0.f, (_Float16)0.f};
  h2v one2  = {(_Float16)1.f, (_Float16)1.f};
  h2v big2  = {(_Float16)60000.f, (_Float16)60000.f};
#pragma unroll
  for (int i = 0; i < 16; i++) {
    h2v d = __builtin_elementwise_max(zh[i] - t2, zero2);
    ff = __builtin_amdgcn_fdot2(d, d, ff, false);
    gg = __builtin_amdgcn_fdot2(d, one2, gg, false);
    h2v mm = __builtin_elementwise_min(d * big2, one2);
    cc = __builtin_amdgcn_fdot2(mm, one2, cc, false);
  }
#else
#pragma unroll
  for (int i = 0; i < 16; i++) {
#pragma unroll
    for (int j = 0; j < 2; j++) {
      float z = (float)zh[i][j];
      float d = fmaxf(z - tau, 0.f);
      ff = fmaf(d, d, ff);
      gg += d;
      cc += (d > 0.f) ? 1.f : 0.f;
    }
  }
#endif
  f = ff; g = gg; c = cc;
}

// frozen-support exact solve (Michelot step); Newton-back if overshot
__device__ __forceinline__ float nstep(float tau, float f, float g, float c, float m) {
  float num  = f - 1.0f;
  float disc = fmaxf(g*g - c*num, 0.f);
  float den  = (num >= 0.f) ? (g + sqrtf(disc)) : (2.0f * g);
  float t = tau + num / fmaxf(den, 1e-12f);
  return fminf(t, m - 0.01f);    // tau* <= m - 1/sqrt(2048); keeps support >= 1
}

// ---------------------------------------------------------------- fused attention
// Block = 16 q-rows of one (b,h); 256 thr = 4 waves; grid 768 = EXACTLY 3
// blocks/CU (12 waves/CU from 3 independent blocks -> barriers and load
// latency overlap across blocks, the proj_mfma mechanism). k in 4 chunks of
// 512. QK^T SWAPPED (A=K, B=Q) -> packed h4 LDS stores. z fp16 in REGISTERS
// (wave w owns q-rows w*4..w*4+3: 64 VGPRs). Ping-pong LDS (2 x 16.6 KB) ->
// 1 barrier/chunk, 8 total, each syncing only 4 waves. Newton wave-local.
// PV: wave w owns d [w*32, w*32+32).
__global__ __launch_bounds__(256, 3) void attn_k(const unsigned short* __restrict__ Qb,
    const unsigned short* __restrict__ Kb, const _Float16* __restrict__ VTb,
    float* __restrict__ AO) {
  __shared__ _Float16 zc[2][QT * ZP];     // 2 x 16640 B

  int tid = threadIdx.x, lane = tid & 63, w = tid >> 6;   // w 0..3
  int g = lane >> 4, li = lane & 15;
  // bijective XCD swizzle: 768 blocks = 8 XCDs x 96 contiguous
  int swz = (blockIdx.x & 7) * 96 + (blockIdx.x >> 3);
  int bh = swz / (NSEQ/QT), qb = swz % (NSEQ/QT);         // NSEQ/QT = 128
  int qbase = qb * QT;
  const unsigned short* Qh  = Qb  + (size_t)bh * NSEQ * DK;
  const unsigned short* Kh  = Kb  + (size_t)bh * NSEQ * DK;
  const _Float16*       VTh = VTb + (size_t)bh * DK * NSEQ;
  const float zs = 0.044194173824159216f;   // 0.5 / sqrt(128)

  // Q B-frags: cols q = qbase + li, k-slice ks*32 + g*8 (persistent)
  bf16x8 bq[4];
#pragma unroll
  for (int ks = 0; ks < 4; ks++)
    bq[ks] = *(const bf16x8*)(Qh + (size_t)(qbase + li)*DK + ks*32 + g*8);

  // ---- Phase 1: QK^T in 4 chunks of 512 k (swapped: A=K rows, B=Q cols)
  // D row = k = kt*16+g*4+r, col = q = li -> packed h4 store z[q][k].
  h8 zr[4][4];   // [row r][chunk c]; wave w owns q rows w*4..w*4+3
#pragma unroll
  for (int c = 0; c < 4; c++) {
    _Float16* buf = zc[c & 1];
#pragma unroll
    for (int kt = 0; kt < 8; kt++) {
      int krow = c*512 + w*128 + kt*16 + li;
      bf16x8 bk[4];
#pragma unroll
      for (int ks = 0; ks < 4; ks++)
        bk[ks] = *(const bf16x8*)(Kh + (size_t)krow*DK + ks*32 + g*8);
      f32x4 za = (f32x4){0.f,0.f,0.f,0.f};
#pragma unroll
      for (int ks = 0; ks < 4; ks++)
        za = __builtin_amdgcn_mfma_f32_16x16x32_bf16(bk[ks], bq[ks], za, 0, 0, 0);
      h4 p;
#pragma unroll
      for (int r = 0; r < 4; r++) p[r] = (_Float16)(za[r] * zs);
      *(h4*)(buf + (size_t)li*ZP + w*128 + kt*16 + g*4) = p;
    }
    __syncthreads();   // chunk staged; ping-pong makes one barrier sufficient
#pragma unroll
    for (int r = 0; r < 4; r++)
      zr[r][c] = *(const h8*)(buf + (size_t)(w*4 + r)*ZP + lane*8);
  }

  // ---- Phase 2: wave-local Newton on rows w*4..w*4+3 (no LDS, no barriers)
  float tau[4], mx[4];
#pragma unroll
  for (int r = 0; r < 4; r++) {
    union { h8 v[4]; h2v h[16]; } u;
#pragma unroll
    for (int c = 0; c < 4; c++) u.v[c] = zr[r][c];
    h2v m2 = u.h[0];
#pragma unroll
    for (int i = 1; i < 16; i++) m2 = __builtin_elementwise_max(m2, u.h[i]);
    float m = fmaxf((float)m2[0], (float)m2[1]);
#pragma unroll
    for (int off = 32; off > 0; off >>= 1) m = fmaxf(m, __shfl_xor(m, off));
    mx[r] = m;
    tau[r] = m - 1.0f;
  }
  for (int it = 0; it < NEWTON_IT; ++it) {
    float f[4], gg[4], cc[4];
#pragma unroll
    for (int r = 0; r < 4; r++) {
      union { h8 v[4]; h2v h[16]; } ur;
#pragma unroll
      for (int c = 0; c < 4; c++) ur.v[c] = zr[r][c];
      scan16(ur.h, tau[r], f[r], gg[r], cc[r]);
    }
#pragma unroll
    for (int off = 32; off > 0; off >>= 1) {
#pragma unroll
      for (int r = 0; r < 4; r++) {
        f[r]  += __shfl_xor(f[r],  off);
        gg[r] += __shfl_xor(gg[r], off);
        cc[r] += __shfl_xor(cc[r], off);
      }
    }
#pragma unroll
    for (int r = 0; r < 4; r++) tau[r] = nstep(tau[r], f[r], gg[r], cc[r], mx[r]);
  }

  // ---- Phase 3: PV in 4 chunks. P rebuilt from zr -> LDS (ping-pong); MFMA vs V^T.
  // wave w owns d in [w*32, w*32+32): pacc[dt], dt = 0,1.
  int d0 = w * 32;
  f32x4 pacc[2];
  pacc[0] = (f32x4){0.f,0.f,0.f,0.f};
  pacc[1] = (f32x4){0.f,0.f,0.f,0.f};
#pragma unroll
  for (int c = 0; c < 4; c++) {
    _Float16* buf = zc[c & 1];
#pragma unroll
    for (int r = 0; r < 4; r++) {
      union { h8 v; h2v h[4]; } u;
      u.v = zr[r][c];
      _Float16 th = (_Float16)tau[r];
      h2v t2 = {th, th};
      h2v zero2 = {(_Float16)0.f, (_Float16)0.f};
#pragma unroll
      for (int j = 0; j < 4; j++) {
        h2v d = __builtin_elementwise_max(u.h[j] - t2, zero2);
        u.h[j] = d * d;
      }
      *(h8*)(buf + (size_t)(w*4 + r)*ZP + lane*8) = u.v;
    }
    __syncthreads();   // P chunk staged; ping-pong protects prev chunk's reads
#pragma unroll
    for (int kk = 0; kk < 16; kk++) {
      h8 pa  = *(const h8*)(buf + (size_t)li*ZP + kk*32 + g*8);
      h8 bv0 = *(const h8*)(VTh + (size_t)(d0 + li)*NSEQ + c*512 + kk*32 + g*8);
      h8 bv1 = *(const h8*)(VTh + (size_t)(d0 + 16 + li)*NSEQ + c*512 + kk*32 + g*8);
      pacc[0] = __builtin_amdgcn_mfma_f32_16x16x32_f16(pa, bv0, pacc[0], 0, 0, 0);
      pacc[1] = __builtin_amdgcn_mfma_f32_16x16x32_f16(pa, bv1, pacc[1], 0, 0, 0);
    }
  }

  // ---- epilogue: out rows q = qbase + g*4 + r, col d = d0 + dt*16 + li
  int b = bh / NH, h = bh % NH;
#pragma unroll
  for (int dt = 0; dt < 2; dt++)
#pragma unroll
    for (int r = 0; r < 4; r++)
      AO[((size_t)b*NSEQ + qbase + g*4 + r)*DM + h*DK + d0 + dt*16 + li] = pacc[dt][r];
}

// ---------------------------------------------------------------- LN + residual
__global__ __launch_bounds__(256) void ln_k(const float* __restrict__ AO,
    const float* __restrict__ xT, const float* __restrict__ ga,
    const float* __restrict__ gb, float* __restrict__ outp) {
  int lane = threadIdx.x & 63;
  int wave = threadIdx.x >> 6;
  int row  = blockIdx.x * 4 + wave;
  const float* ao = AO + (size_t)row*DM;
  float2 c0 = *(const float2*)(ao + lane*2);
  float2 c1 = *(const float2*)(ao + 128 + lane*2);
  float2 c2 = *(const float2*)(ao + 256 + lane*2);
  float s  = c0.x + c0.y + c1.x + c1.y + c2.x + c2.y;
  float ss = c0.x*c0.x + c0.y*c0.y + c1.x*c1.x + c1.y*c1.y + c2.x*c2.x + c2.y*c2.y;
#pragma unroll
  for (int off = 32; off > 0; off >>= 1) {
    s  += __shfl_xor(s,  off);
    ss += __shfl_xor(ss, off);
  }
  float mean = s * (1.0f / 384.0f);
  float var  = (ss - 384.0f*mean*mean) * (1.0f / 383.0f);   // Bessel (n-1)
  var = fmaxf(var, 0.f);
  float inv = 1.0f / (sqrtf(var) + 1e-6f);                  // eps added to STD
  const float* xr = xT + (size_t)row*DM;
  float* op = outp + (size_t)row*DM;
#pragma unroll
  for (int ch = 0; ch < 3; ch++) {
    int i0 = ch*128 + lane*2;
    float2 g  = *(const float2*)(ga + i0);
    float2 bb = *(const float2*)(gb + i0);
    float2 xv = *(const float2*)(xr + i0);
    float2 av = (ch == 0) ? c0 : (ch == 1) ? c1 : c2;
    float2 o;
    o.x = g.x*(av.x - mean)*inv + bb.x + xv.x;
    o.y = g.y*(av.y - mean)*inv + bb.y + xv.y;
    *(float2*)(op + i0) = o;
  }
}

// ---------------------------------------------------------------- launch
extern "C" void kernel_launch(void* const* d_in, const int* in_sizes, int n_in,
                              void* d_out, int out_size, void* d_ws, size_t ws_size,
                              hipStream_t stream) {
  const float* x  = (const float*)d_in[0];
  const float* wq = (const float*)d_in[1];
  const float* bq = (const float*)d_in[2];
  const float* wk = (const float*)d_in[3];
  const float* bk = (const float*)d_in[4];
  const float* wv = (const float*)d_in[5];
  const float* bv = (const float*)d_in[6];
  const float* la = (const float*)d_in[7];
  const float* lb = (const float*)d_in[8];
  float* out = (float*)d_out;

  // ws: xT f32 | AO f32 | Qb bf16 | Kb bf16 | VT f16 | xbf bf16 | wbf bf16
  char* wsb = (char*)d_ws;
  float* xT = (float*)wsb;
  float* AO = (float*)(wsb + (size_t)SEG*4);
  unsigned short* Qb  = (unsigned short*)(wsb + (size_t)SEG*8);
  unsigned short* Kb  = (unsigned short*)(wsb + (size_t)SEG*8 + (size_t)SEG*2);
  unsigned short* VT  = (unsigned short*)(wsb + (size_t)SEG*8 + (size_t)SEG*4);
  unsigned short* xbf = (unsigned short*)(wsb + (size_t)SEG*8 + (size_t)SEG*6);
  unsigned short* wbf = (unsigned short*)(wsb + (size_t)SEG*8 + (size_t)SEG*8);

  hipLaunchKernelGGL(transpose_k, dim3(NSEQ/32, DM/32, BATCH), dim3(256), 0, stream,
                     x, xT, xbf);
  hipLaunchKernelGGL(wconv_k, dim3(DM*DM/1024, 3), dim3(256), 0, stream, wq, wk, wv, wbf);
  hipLaunchKernelGGL(proj_mfma_k, dim3(NTOK/128, NH, 3), dim3(256), 0, stream,
                     xbf, wbf, bq, bk, bv, Qb, Kb, VT);
  hipLaunchKernelGGL(attn_k, dim3(BATCH*NH*(NSEQ/QT)), dim3(256), 0, stream,
                     Qb, Kb, (const _Float16*)VT, AO);
  hipLaunchKernelGGL(ln_k, dim3(BATCH*NSEQ/4), dim3(256), 0, stream, AO, xT, la, lb, out);
}

// Round 13
// 118.616 us; speedup vs baseline: 1.6017x; 1.1342x over previous
//
#include <hip/hip_runtime.h>
#include <hip/hip_fp16.h>
#include <math.h>

// HieraFormer fused block:
//   transpose -> MFMA QKV proj -> fused attn (global_load_lds-staged K/V,
//   chunked swapped-MFMA QK^T -> reg-resident fp16 z -> wave-local quadratic
//   Newton -> chunked MFMA PV) -> LN+residual.
// B=2, D_MODEL=384, H=3, D_K=128, N=2048.
#define DM   384
#define NH   3
#define DK   128
#define NSEQ 2048
#define BATCH 2
#define NTOK (BATCH*NSEQ)      // 4096
#define SEG  (BATCH*NSEQ*DM)   // 1572864 elements
#define NEWTON_IT 6
#define QT   16                // q-rows per block
#define ZP   520               // z LDS pitch in halves (512 + 8)

typedef __attribute__((ext_vector_type(8))) short     bf16x8;
typedef __attribute__((ext_vector_type(4))) float     f32x4;
typedef __attribute__((ext_vector_type(8))) _Float16  h8;
typedef __attribute__((ext_vector_type(4))) _Float16  h4;
typedef __attribute__((ext_vector_type(2))) _Float16  h2v;

#if __has_builtin(__builtin_amdgcn_fdot2)
#define HAVE_FDOT2 1
#else
#define HAVE_FDOT2 0
#endif

// global -> LDS async DMA, 16B per lane. Global src is PER-LANE; LDS dest is
// wave-uniform (HW adds lane*16). Frees VGPRs -> deep outstanding-load queue.
typedef const unsigned int __attribute__((address_space(1)))* gas1_t;
typedef unsigned int __attribute__((address_space(3)))* las3_t;
__device__ __forceinline__ void gll16(const void* g, void* l) {
  __builtin_amdgcn_global_load_lds((gas1_t)g, (las3_t)l, 16, 0, 0);
}

__device__ __forceinline__ unsigned short f2bf(float f) {
  unsigned u = __builtin_bit_cast(unsigned, f);
  u += 0x7FFFu + ((u >> 16) & 1u);          // RNE
  return (unsigned short)(u >> 16);
}

// ---------------------------------------------------------------- transpose
__global__ __launch_bounds__(256) void transpose_k(const float* __restrict__ x,
                                                   float* __restrict__ xT,
                                                   unsigned short* __restrict__ xbf) {
  __shared__ float tile[32][33];
  int b  = blockIdx.z;
  int cB = blockIdx.y * 32;
  int nB = blockIdx.x * 32;
  int tx = threadIdx.x & 31, ty = threadIdx.x >> 5;
#pragma unroll
  for (int i = 0; i < 4; i++)
    tile[ty + i*8][tx] = x[((size_t)b*DM + cB + ty + i*8)*NSEQ + nB + tx];
  __syncthreads();
#pragma unroll
  for (int i = 0; i < 4; i++) {
    float v = tile[tx][ty + i*8];
    size_t row = (size_t)b*NSEQ + nB + ty + i*8;
    xT [row*DM + cB + tx] = v;
    xbf[row*DM + cB + tx] = f2bf(v);
  }
}

// ---------------------------------------------------------------- weight convert
__global__ __launch_bounds__(256) void wconv_k(const float* __restrict__ wq,
    const float* __restrict__ wk, const float* __restrict__ wv,
    unsigned short* __restrict__ wbf) {
  int pj = blockIdx.y;
  const float* src = (pj == 0) ? wq : (pj == 1) ? wk : wv;
  int i = (blockIdx.x * 256 + threadIdx.x) * 4;
  float4 v = *(const float4*)(src + i);
  ushort4 o;
  o.x = f2bf(v.x); o.y = f2bf(v.y); o.z = f2bf(v.z); o.w = f2bf(v.w);
  *(ushort4*)(wbf + (size_t)pj*DM*DM + i) = o;
}

// ---------------------------------------------------------------- MFMA projections
// Q,K -> bf16 [b][h][n][d];  V -> fp16 transposed VT [b][h][d][n].
__global__ __launch_bounds__(256) void proj_mfma_k(
    const unsigned short* __restrict__ xbf,   // [NTOK][DM]
    const unsigned short* __restrict__ wbf,   // [3][DM][DM]
    const float* __restrict__ bq, const float* __restrict__ bk, const float* __restrict__ bv,
    unsigned short* __restrict__ Qo, unsigned short* __restrict__ Ko,
    unsigned short* __restrict__ VTo) {      // VT stored as f16 bit-pattern
  int tid = threadIdx.x, lane = tid & 63, w = tid >> 6;
  int g = lane >> 4, li = lane & 15;
  int wr = w >> 1, wc = w & 1;
  int h  = blockIdx.y;
  int pj = blockIdx.z;
  const unsigned short* wp0 = wbf + (size_t)pj * DM * DM;
  const float* bias = (pj == 0) ? bq : (pj == 1) ? bk : bv;

  const unsigned short *Am, *Bn;
  int mB, nB;
  if (pj < 2) { Am = wp0; mB = h*128 + wr*64;          Bn = xbf; nB = blockIdx.x*128 + wc*64; }
  else        { Am = xbf; mB = blockIdx.x*128 + wr*64; Bn = wp0; nB = h*128 + wc*64; }

  f32x4 acc[4][4];
#pragma unroll
  for (int fi = 0; fi < 4; fi++)
#pragma unroll
    for (int fj = 0; fj < 4; fj++) acc[fi][fj] = (f32x4){0.f, 0.f, 0.f, 0.f};

#pragma unroll 2
  for (int ks = 0; ks < DM/32; ks++) {
    bf16x8 af[4], bf[4];
#pragma unroll
    for (int fi = 0; fi < 4; fi++)
      af[fi] = *(const bf16x8*)(Am + (size_t)(mB + fi*16 + li)*DM + ks*32 + g*8);
#pragma unroll
    for (int fj = 0; fj < 4; fj++)
      bf[fj] = *(const bf16x8*)(Bn + (size_t)(nB + fj*16 + li)*DM + ks*32 + g*8);
#pragma unroll
    for (int fi = 0; fi < 4; fi++)
#pragma unroll
      for (int fj = 0; fj < 4; fj++)
        acc[fi][fj] = __builtin_amdgcn_mfma_f32_16x16x32_bf16(af[fi], bf[fj], acc[fi][fj], 0, 0, 0);
  }

  if (pj < 2) {
    unsigned short* dst = (pj == 0) ? Qo : Ko;
#pragma unroll
    for (int fi = 0; fi < 4; fi++) {
      int o0 = mB + fi*16 + g*4;
      float4 bb = *(const float4*)(bias + o0);
      int d0 = o0 & 127;
#pragma unroll
      for (int fj = 0; fj < 4; fj++) {
        int tok = nB + fj*16 + li;
        int bb_ = tok >> 11, n = tok & 2047;
        ushort4 v4;
        v4.x = f2bf(acc[fi][fj][0] + bb.x);
        v4.y = f2bf(acc[fi][fj][1] + bb.y);
        v4.z = f2bf(acc[fi][fj][2] + bb.z);
        v4.w = f2bf(acc[fi][fj][3] + bb.w);
        *(ushort4*)(dst + ((size_t)(bb_*NH + h)*NSEQ + n)*DK + d0) = v4;
      }
    }
  } else {
#pragma unroll
    for (int fj = 0; fj < 4; fj++) {
      int o  = nB + fj*16 + li;
      float bb = bias[o];
      int d  = o & 127;
#pragma unroll
      for (int fi = 0; fi < 4; fi++) {
        int tok0 = mB + fi*16 + g*4;
        int bb_ = tok0 >> 11, n0 = tok0 & 2047;
        ushort4 v4;
        v4.x = __builtin_bit_cast(unsigned short, (_Float16)(acc[fi][fj][0] + bb));
        v4.y = __builtin_bit_cast(unsigned short, (_Float16)(acc[fi][fj][1] + bb));
        v4.z = __builtin_bit_cast(unsigned short, (_Float16)(acc[fi][fj][2] + bb));
        v4.w = __builtin_bit_cast(unsigned short, (_Float16)(acc[fi][fj][3] + bb));
        *(ushort4*)(VTo + ((size_t)(bb_*NH + h)*DK + d)*NSEQ + n0) = v4;
      }
    }
  }
}

// ---------------------------------------------------------------- entmax helpers
__device__ __forceinline__ void scan16(const h2v* zh, float tau,
                                       float& f, float& g, float& c) {
  float ff = 0.f, gg = 0.f, cc = 0.f;
#if HAVE_FDOT2
  _Float16 th = (_Float16)tau;
  h2v t2 = {th, th};
  h2v zero2 = {(_Float16)0.f, (_Float16)0.f};
  h2v one2  = {(_Float16)1.f, (_Float16)1.f};
  h2v big2  = {(_Float16)60000.f, (_Float16)60000.f};
#pragma unroll
  for (int i = 0; i < 16; i++) {
    h2v d = __builtin_elementwise_max(zh[i] - t2, zero2);
    ff = __builtin_amdgcn_fdot2(d, d, ff, false);
    gg = __builtin_amdgcn_fdot2(d, one2, gg, false);
    h2v mm = __builtin_elementwise_min(d * big2, one2);
    cc = __builtin_amdgcn_fdot2(mm, one2, cc, false);
  }
#else
#pragma unroll
  for (int i = 0; i < 16; i++) {
#pragma unroll
    for (int j = 0; j < 2; j++) {
      float z = (float)zh[i][j];
      float d = fmaxf(z - tau, 0.f);
      ff = fmaf(d, d, ff);
      gg += d;
      cc += (d > 0.f) ? 1.f : 0.f;
    }
  }
#endif
  f = ff; g = gg; c = cc;
}

// frozen-support exact solve (Michelot step); Newton-back if overshot
__device__ __forceinline__ float nstep(float tau, float f, float g, float c, float m) {
  float num  = f - 1.0f;
  float disc = fmaxf(g*g - c*num, 0.f);
  float den  = (num >= 0.f) ? (g + sqrtf(disc)) : (2.0f * g);
  float t = tau + num / fmaxf(den, 1e-12f);
  return fminf(t, m - 0.01f);    // tau* <= m - 1/sqrt(2048); keeps support >= 1
}

// ---------------------------------------------------------------- fused attention
// Block = 16 q-rows of one (b,h); 256 thr = 4 waves; grid 768 = 3 blocks/CU.
// K and V are staged into LDS via global_load_lds (16B, double-buffered 16KB
// sub-tiles) -> ~16KB outstanding per wave without consuming VGPRs (fixes the
// outstanding-bytes limit that capped R7-R12 at ~105us). gll writes LINEAR LDS;
// bank conflicts on the MFMA-operand ds_read_b128 (row stride 256B = 0 mod 32
// banks) are fixed by pre-swizzling the GLOBAL source chunk (ch ^= row&7) and
// applying the same XOR on reads (G21/m173: both-sides involution).
// z fp16 in REGISTERS (wave w owns q-rows w*4..w*4+3). Newton wave-local.
__global__ __launch_bounds__(256, 3) void attn_k(const unsigned short* __restrict__ Qb,
    const unsigned short* __restrict__ Kb, const _Float16* __restrict__ VTb,
    float* __restrict__ AO) {
  __shared__ _Float16 stg[2][8192];       // 2 x 16 KB staging (K, then V)
  __shared__ _Float16 zbuf[QT * ZP];      // 16.6 KB z / P tile

  int tid = threadIdx.x, lane = tid & 63, w = tid >> 6;   // w 0..3
  int g = lane >> 4, li = lane & 15;
  // bijective XCD swizzle: 768 blocks = 8 XCDs x 96 contiguous
  int swz = (blockIdx.x & 7) * 96 + (blockIdx.x >> 3);
  int bh = swz / (NSEQ/QT), qb = swz % (NSEQ/QT);         // NSEQ/QT = 128
  int qbase = qb * QT;
  const unsigned short* Qh  = Qb  + (size_t)bh * NSEQ * DK;
  const unsigned short* Kh  = Kb  + (size_t)bh * NSEQ * DK;
  const _Float16*       VTh = VTb + (size_t)bh * DK * NSEQ;
  const float zs = 0.044194173824159216f;   // 0.5 / sqrt(128)

  // Q B-frags: cols q = qbase + li, k-slice ks*32 + g*8 (persistent)
  bf16x8 bq[4];
#pragma unroll
  for (int ks = 0; ks < 4; ks++)
    bq[ks] = *(const bf16x8*)(Qh + (size_t)(qbase + li)*DK + ks*32 + g*8);

  // ---- staging helpers (16 KB sub-tile = 4 gll issues per thread) ----
  // K sub: 64 k-rows x 128 halves, row-major, source chunk pre-swizzled.
  auto stageK = [&](int c, int s, int b) {
#pragma unroll
    for (int j = 0; j < 4; j++) {
      int idx   = (j*4 + w)*64 + lane;          // 16B-chunk index 0..1023
      int row_l = idx >> 4;                     // 0..63
      int ch    = idx & 15;
      const unsigned short* src = Kh + (size_t)(c*512 + s*64 + row_l)*DK
                                     + ((ch ^ (row_l & 7)) * 8);
      void* dst = (void*)((char*)&stg[b][0] + (size_t)(j*4 + w) * 1024); // wave-uniform
      gll16(src, dst);
    }
  };
  // V sub: 128 d-rows x 64 halves (k), row-major, source chunk pre-swizzled.
  auto stageV = [&](int c, int s, int b) {
#pragma unroll
    for (int j = 0; j < 4; j++) {
      int idx = (j*4 + w)*64 + lane;            // 16B-chunk index 0..1023
      int dr  = idx >> 3;                       // 0..127
      int ch  = idx & 7;
      const _Float16* src = VTh + (size_t)dr*NSEQ + c*512 + s*64
                                + ((ch ^ (dr & 7)) * 8);
      void* dst = (void*)((char*)&stg[b][0] + (size_t)(j*4 + w) * 1024); // wave-uniform
      gll16(src, dst);
    }
  };

  // ---- Phase 1: QK^T, 4 chunks of 512 k, each as 8 staged subs of 64 rows.
  // Swapped operands (A = K rows, B = Q cols): D row = k, col = q -> h4 store.
  h8 zr[4][4];   // [row r][chunk c]; wave w owns q rows w*4..w*4+3
#pragma unroll
  for (int c = 0; c < 4; c++) {
    stageK(c, 0, 0);
    __syncthreads();                            // sub 0 staged
    for (int s = 0; s < 8; s++) {
      if (s < 7) stageK(c, s + 1, (s + 1) & 1);
      const _Float16* kb = &stg[s & 1][0];
      bf16x8 bk[4];
#pragma unroll
      for (int ks = 0; ks < 4; ks++)
        bk[ks] = *(const bf16x8*)(kb + (size_t)(w*16 + li)*128
                                     + (((ks*4 + g) ^ (li & 7)) * 8));
      f32x4 za = (f32x4){0.f,0.f,0.f,0.f};
#pragma unroll
      for (int ks = 0; ks < 4; ks++)
        za = __builtin_amdgcn_mfma_f32_16x16x32_bf16(bk[ks], bq[ks], za, 0, 0, 0);
      h4 p;
#pragma unroll
      for (int r = 0; r < 4; r++) p[r] = (_Float16)(za[r] * zs);
      *(h4*)(zbuf + (size_t)li*ZP + s*64 + w*16 + g*4) = p;
      __syncthreads();                          // next sub staged + z writes visible
    }
#pragma unroll
    for (int r = 0; r < 4; r++)
      zr[r][c] = *(const h8*)(zbuf + (size_t)(w*4 + r)*ZP + lane*8);
    __syncthreads();                            // zr reads done; zbuf reusable
  }

  // ---- Phase 2: wave-local Newton on rows w*4..w*4+3 (no LDS, no barriers)
  float tau[4], mx[4];
#pragma unroll
  for (int r = 0; r < 4; r++) {
    union { h8 v[4]; h2v h[16]; } u;
#pragma unroll
    for (int c = 0; c < 4; c++) u.v[c] = zr[r][c];
    h2v m2 = u.h[0];
#pragma unroll
    for (int i = 1; i < 16; i++) m2 = __builtin_elementwise_max(m2, u.h[i]);
    float m = fmaxf((float)m2[0], (float)m2[1]);
#pragma unroll
    for (int off = 32; off > 0; off >>= 1) m = fmaxf(m, __shfl_xor(m, off));
    mx[r] = m;
    tau[r] = m - 1.0f;
  }
  for (int it = 0; it < NEWTON_IT; ++it) {
    float f[4], gg[4], cc[4];
#pragma unroll
    for (int r = 0; r < 4; r++) {
      union { h8 v[4]; h2v h[16]; } ur;
#pragma unroll
      for (int c = 0; c < 4; c++) ur.v[c] = zr[r][c];
      scan16(ur.h, tau[r], f[r], gg[r], cc[r]);
    }
#pragma unroll
    for (int off = 32; off > 0; off >>= 1) {
#pragma unroll
      for (int r = 0; r < 4; r++) {
        f[r]  += __shfl_xor(f[r],  off);
        gg[r] += __shfl_xor(gg[r], off);
        cc[r] += __shfl_xor(cc[r], off);
      }
    }
#pragma unroll
    for (int r = 0; r < 4; r++) tau[r] = nstep(tau[r], f[r], gg[r], cc[r], mx[r]);
  }

  // ---- Phase 3: PV, 4 chunks; P rebuilt into zbuf; V staged in 8 subs/chunk.
  f32x4 pacc[2];
  pacc[0] = (f32x4){0.f,0.f,0.f,0.f};
  pacc[1] = (f32x4){0.f,0.f,0.f,0.f};
#pragma unroll
  for (int c = 0; c < 4; c++) {
    // P = relu(z - tau)^2 for own rows -> zbuf (full 512-k chunk)
#pragma unroll
    for (int r = 0; r < 4; r++) {
      union { h8 v; h2v h[4]; } u;
      u.v = zr[r][c];
      _Float16 th = (_Float16)tau[r];
      h2v t2 = {th, th};
      h2v zero2 = {(_Float16)0.f, (_Float16)0.f};
#pragma unroll
      for (int j = 0; j < 4; j++) {
        h2v d = __builtin_elementwise_max(u.h[j] - t2, zero2);
        u.h[j] = d * d;
      }
      *(h8*)(zbuf + (size_t)(w*4 + r)*ZP + lane*8) = u.v;
    }
    stageV(c, 0, 0);
    __syncthreads();                            // P visible + V sub 0 staged
    for (int s = 0; s < 8; s++) {
      if (s < 7) stageV(c, s + 1, (s + 1) & 1);
      const _Float16* vb = &stg[s & 1][0];
#pragma unroll
      for (int k2 = 0; k2 < 2; k2++) {
        h8 pa = *(const h8*)(zbuf + (size_t)li*ZP + s*64 + k2*32 + g*8);
#pragma unroll
        for (int dt = 0; dt < 2; dt++) {
          int dr = w*32 + dt*16 + li;           // d-row 0..127
          h8 bv = *(const h8*)(vb + (size_t)dr*64 + (((k2*4 + g) ^ (dr & 7)) * 8));
          pacc[dt] = __builtin_amdgcn_mfma_f32_16x16x32_f16(pa, bv, pacc[dt], 0, 0, 0);
        }
      }
      __syncthreads();                          // next V sub staged; vb reads done
    }
  }

  // ---- epilogue: out rows q = qbase + g*4 + r, col d = w*32 + dt*16 + li
  int b = bh / NH, h = bh % NH;
#pragma unroll
  for (int dt = 0; dt < 2; dt++)
#pragma unroll
    for (int r = 0; r < 4; r++)
      AO[((size_t)b*NSEQ + qbase + g*4 + r)*DM + h*DK + w*32 + dt*16 + li] = pacc[dt][r];
}

// ---------------------------------------------------------------- LN + residual
__global__ __launch_bounds__(256) void ln_k(const float* __restrict__ AO,
    const float* __restrict__ xT, const float* __restrict__ ga,
    const float* __restrict__ gb, float* __restrict__ outp) {
  int lane = threadIdx.x & 63;
  int wave = threadIdx.x >> 6;
  int row  = blockIdx.x * 4 + wave;
  const float* ao = AO + (size_t)row*DM;
  float2 c0 = *(const float2*)(ao + lane*2);
  float2 c1 = *(const float2*)(ao + 128 + lane*2);
  float2 c2 = *(const float2*)(ao + 256 + lane*2);
  float s  = c0.x + c0.y + c1.x + c1.y + c2.x + c2.y;
  float ss = c0.x*c0.x + c0.y*c0.y + c1.x*c1.x + c1.y*c1.y + c2.x*c2.x + c2.y*c2.y;
#pragma unroll
  for (int off = 32; off > 0; off >>= 1) {
    s  += __shfl_xor(s,  off);
    ss += __shfl_xor(ss, off);
  }
  float mean = s * (1.0f / 384.0f);
  float var  = (ss - 384.0f*mean*mean) * (1.0f / 383.0f);   // Bessel (n-1)
  var = fmaxf(var, 0.f);
  float inv = 1.0f / (sqrtf(var) + 1e-6f);                  // eps added to STD
  const float* xr = xT + (size_t)row*DM;
  float* op = outp + (size_t)row*DM;
#pragma unroll
  for (int ch = 0; ch < 3; ch++) {
    int i0 = ch*128 + lane*2;
    float2 g  = *(const float2*)(ga + i0);
    float2 bb = *(const float2*)(gb + i0);
    float2 xv = *(const float2*)(xr + i0);
    float2 av = (ch == 0) ? c0 : (ch == 1) ? c1 : c2;
    float2 o;
    o.x = g.x*(av.x - mean)*inv + bb.x + xv.x;
    o.y = g.y*(av.y - mean)*inv + bb.y + xv.y;
    *(float2*)(op + i0) = o;
  }
}

// ---------------------------------------------------------------- launch
extern "C" void kernel_launch(void* const* d_in, const int* in_sizes, int n_in,
                              void* d_out, int out_size, void* d_ws, size_t ws_size,
                              hipStream_t stream) {
  const float* x  = (const float*)d_in[0];
  const float* wq = (const float*)d_in[1];
  const float* bq = (const float*)d_in[2];
  const float* wk = (const float*)d_in[3];
  const float* bk = (const float*)d_in[4];
  const float* wv = (const float*)d_in[5];
  const float* bv = (const float*)d_in[6];
  const float* la = (const float*)d_in[7];
  const float* lb = (const float*)d_in[8];
  float* out = (float*)d_out;

  // ws: xT f32 | AO f32 | Qb bf16 | Kb bf16 | VT f16 | xbf bf16 | wbf bf16
  char* wsb = (char*)d_ws;
  float* xT = (float*)wsb;
  float* AO = (float*)(wsb + (size_t)SEG*4);
  unsigned short* Qb  = (unsigned short*)(wsb + (size_t)SEG*8);
  unsigned short* Kb  = (unsigned short*)(wsb + (size_t)SEG*8 + (size_t)SEG*2);
  unsigned short* VT  = (unsigned short*)(wsb + (size_t)SEG*8 + (size_t)SEG*4);
  unsigned short* xbf = (unsigned short*)(wsb + (size_t)SEG*8 + (size_t)SEG*6);
  unsigned short* wbf = (unsigned short*)(wsb + (size_t)SEG*8 + (size_t)SEG*8);

  hipLaunchKernelGGL(transpose_k, dim3(NSEQ/32, DM/32, BATCH), dim3(256), 0, stream,
                     x, xT, xbf);
  hipLaunchKernelGGL(wconv_k, dim3(DM*DM/1024, 3), dim3(256), 0, stream, wq, wk, wv, wbf);
  hipLaunchKernelGGL(proj_mfma_k, dim3(NTOK/128, NH, 3), dim3(256), 0, stream,
                     xbf, wbf, bq, bk, bv, Qb, Kb, VT);
  hipLaunchKernelGGL(attn_k, dim3(BATCH*NH*(NSEQ/QT)), dim3(256), 0, stream,
                     Qb, Kb, (const _Float16*)VT, AO);
  hipLaunchKernelGGL(ln_k, dim3(BATCH*NSEQ/4), dim3(256), 0, stream, AO, xT, la, lb, out);
}